// Round 2
// baseline (1586.696 us; speedup 1.0000x reference)
//
#include <hip/hip_runtime.h>
#include <hip/hip_fp16.h>

// GPTQ int4 dequant + GEMM, decomposed (R2).
//
// R1 post-mortem: packed-fp16 dequant cut VALUBusy 62->48% but dur went UP
// (1210->1365us): the 2-barrier stage->compute structure is latency-bound, and
// the staging work is redundant (x converted 86x, W dequanted 64x). Fix the
// algorithm, not the ops:
//   prepass 1: x fp32 -> A16 fp16 (RTE, bit-exact vs ref)         ~32us
//   prepass 2: qweight -> Wt[n][k] fp16 (bit-trick dequant)       ~20us
//   main:      fp16 B^T GEMM, m97 structure: 128x128 tile, BK=64,
//              ALL staging via global_load_lds width=16 (zero staging VALU).
//              Guide ladder step 3: 874-912 TF measured at this structure.
// Workspace: 67MB (A16) + 90MB (Wt) = 157.3MB. Falls back to the fused kernel
// if ws_size is insufficient.
//
// Numerics (bit-exact to reference):
//   nibble->fp16: (raw>>4p & 0x000F000F)|0x64006400 == {1024+n_p, 1024+n_{p+4}}
//   (w-z) exact in fp16 (ints<=15, ulp=1 at 1024); fp16 mul = one RTE round of
//   the exact product == ref's fp32-product->RTE-fp16 cast.

#define M_TOT 8192
#define N_TOT 11008
#define K_TOT 4096

typedef _Float16 half2v __attribute__((ext_vector_type(2)));
typedef _Float16 half8 __attribute__((ext_vector_type(8)));
typedef float float4v __attribute__((ext_vector_type(4)));

// ---------------- prepass 1: x fp32 -> fp16 ----------------
__global__ __launch_bounds__(256) void cvt_x_fp16(const float* __restrict__ x,
                                                  _Float16* __restrict__ a16) {
    const size_t i = ((size_t)blockIdx.x * 256 + threadIdx.x) * 8;
    float4v v0 = *(const float4v*)(x + i);
    float4v v1 = *(const float4v*)(x + i + 4);
    half8 h;
    h[0] = (_Float16)v0[0]; h[1] = (_Float16)v0[1];
    h[2] = (_Float16)v0[2]; h[3] = (_Float16)v0[3];
    h[4] = (_Float16)v1[0]; h[5] = (_Float16)v1[1];
    h[6] = (_Float16)v1[2]; h[7] = (_Float16)v1[3];
    *(half8*)(a16 + i) = h;
}

// ---------------- prepass 2: qweight -> Wt[n][k] fp16 ----------------
// thread = (n, 4 consecutive qw-rows). Reads coalesced across n (256B/wave);
// writes 64B contiguous per thread (full cachelines, no partial-line RMW).
__global__ __launch_bounds__(256) void dequant_w(const int* __restrict__ qw,
                                                 const unsigned* __restrict__ qz,
                                                 const float* __restrict__ sc,
                                                 _Float16* __restrict__ wt) {
    const int n = blockIdx.x * 256 + threadIdx.x;   // grid.x = 43 -> 11008
    const int r0 = blockIdx.y * 4;                  // grid.y = 128 -> 512 rows
    const int g = r0 >> 4;                          // group = (8*r0)/128
    const _Float16 s_h = (_Float16)sc[g * N_TOT + n];
    half2v sp; sp[0] = s_h; sp[1] = s_h;
    const unsigned zraw = qz[g * (N_TOT / 8) + (n >> 3)];
    const unsigned zn = (zraw >> ((n & 7) * 4)) & 15u;
    const half2v zp = __builtin_bit_cast(half2v, 0x64006400u | zn | (zn << 16));
    _Float16* o = wt + (size_t)n * K_TOT + r0 * 8;
    #pragma unroll
    for (int i = 0; i < 4; ++i) {
        const unsigned raw = (unsigned)qw[(size_t)(r0 + i) * N_TOT + n];
        half8 w;
        #pragma unroll
        for (int p = 0; p < 4; ++p) {
            const unsigned bits = ((raw >> (4 * p)) & 0x000F000Fu) | 0x64006400u;
            half2v d = (__builtin_bit_cast(half2v, bits) - zp) * sp;  // v_pk ops
            w[p]     = d[0];   // k = 8r + p
            w[p + 4] = d[1];   // k = 8r + p + 4
        }
        *(half8*)(o + i * 8) = w;
    }
}

// ---------------- main GEMM: A16[M][K] x Wt[N][K]^T -> out[M][N] ----------------
#define BM 128
#define BN 128
#define BK 64

__global__ __launch_bounds__(256) void gemm_f16(const _Float16* __restrict__ A,
                                                const _Float16* __restrict__ B,
                                                float* __restrict__ out) {
    __shared__ _Float16 As[BM * BK];  // 16 KB, linear (global_load_lds needs linear dest)
    __shared__ _Float16 Bs[BN * BK];  // 16 KB

    const int tid = threadIdx.x;
    const int n0 = blockIdx.x * BN;   // 0..85
    const int m0 = blockIdx.y * BM;   // 0..63

    const int wave = tid >> 6;
    const int lane = tid & 63;
    const int wr = wave >> 1;         // wave row (m), 0..1
    const int wc = wave & 1;          // wave col (n), 0..1
    const int l16 = lane & 15;
    const int quad = lane >> 4;

    // staging geometry: wave w, issue i covers LDS bytes i*4096 + w*1024;
    // lane adds lane*16 (HW). row = i*32 + w*8 + lane/8, k-halves = (lane&7)*8.
    const int srow = wave * 8 + (lane >> 3);
    const int scol = (lane & 7) * 8;

    float4v acc[4][4] = {};

    for (int k0 = 0; k0 < K_TOT; k0 += BK) {
        __syncthreads();  // protect LDS from previous iteration's reads
        #pragma unroll
        for (int i = 0; i < 4; ++i) {
            const _Float16* ga = A + (size_t)(m0 + i * 32 + srow) * K_TOT + k0 + scol;
            __builtin_amdgcn_global_load_lds(
                (const __attribute__((address_space(1))) void*)ga,
                (__attribute__((address_space(3))) void*)&As[(i * 32 + wave * 8) * BK],
                16, 0, 0);
            const _Float16* gb = B + (size_t)(n0 + i * 32 + srow) * K_TOT + k0 + scol;
            __builtin_amdgcn_global_load_lds(
                (const __attribute__((address_space(1))) void*)gb,
                (__attribute__((address_space(3))) void*)&Bs[(i * 32 + wave * 8) * BK],
                16, 0, 0);
        }
        __syncthreads();  // compiler drains vmcnt(0) before barrier

        #pragma unroll
        for (int kk = 0; kk < 2; ++kk) {
            half8 af[4], bf[4];
            #pragma unroll
            for (int i = 0; i < 4; ++i)  // A[m = wr*64+i*16+l16][k = kk*32+quad*8 ..]
                af[i] = *(const half8*)&As[(wr * 64 + i * 16 + l16) * BK + kk * 32 + quad * 8];
            #pragma unroll
            for (int j = 0; j < 4; ++j)  // B[n = wc*64+j*16+l16][k ..]
                bf[j] = *(const half8*)&Bs[(wc * 64 + j * 16 + l16) * BK + kk * 32 + quad * 8];
            #pragma unroll
            for (int i = 0; i < 4; ++i)
                #pragma unroll
                for (int j = 0; j < 4; ++j)
                    acc[i][j] = __builtin_amdgcn_mfma_f32_16x16x32_f16(af[i], bf[j], acc[i][j], 0, 0, 0);
        }
    }

    // epilogue: C/D layout col = lane&15 (n), row = quad*4 + reg (m)
    float* o = out + (size_t)(m0 + wr * 64) * N_TOT + (n0 + wc * 64);
    #pragma unroll
    for (int i = 0; i < 4; ++i)
        #pragma unroll
        for (int j = 0; j < 4; ++j)
            #pragma unroll
            for (int r = 0; r < 4; ++r)
                o[(size_t)(i * 16 + quad * 4 + r) * N_TOT + (j * 16 + l16)] = acc[i][j][r];
}

// ---------------- fallback: fused kernel (R1, verified) ----------------
#define LDK 72

__global__ __launch_bounds__(256) void gptq_fused_gemm(
    const float* __restrict__ x,
    const int* __restrict__ qw,
    const unsigned* __restrict__ qz,
    const float* __restrict__ sc,
    float* __restrict__ out)
{
    __shared__ _Float16 As[BM * LDK];
    __shared__ _Float16 Bs[BN * LDK];

    const int tid = threadIdx.x;
    const int m0 = blockIdx.y * BM;
    const int n0 = blockIdx.x * BN;

    const int wave = tid >> 6;
    const int lane = tid & 63;
    const int wr = wave >> 1;
    const int wc = wave & 1;
    const int l16 = lane & 15;
    const int quad = lane >> 4;

    const int a_k8 = tid & 7;
    const int a_m  = tid >> 3;
    const int b_n  = tid & 127;
    const int b_rr = tid >> 7;
    const int ncol = n0 + b_n;

    float4v acc[4][4] = {};

    for (int k0 = 0; k0 < K_TOT; k0 += BK) {
        __syncthreads();
        {
            const float* src = x + (size_t)(m0 + a_m) * K_TOT + k0 + a_k8 * 8;
            #pragma unroll
            for (int i = 0; i < 4; ++i) {
                const float* p = src + (size_t)(i * 32) * K_TOT;
                float4v v0 = *(const float4v*)p;
                float4v v1 = *(const float4v*)(p + 4);
                half8 h;
                h[0] = (_Float16)v0[0]; h[1] = (_Float16)v1[0];
                h[2] = (_Float16)v0[1]; h[3] = (_Float16)v1[1];
                h[4] = (_Float16)v0[2]; h[5] = (_Float16)v1[2];
                h[6] = (_Float16)v0[3]; h[7] = (_Float16)v1[3];
                *(half8*)&As[(a_m + 32 * i) * LDK + a_k8 * 8] = h;
            }
        }
        {
            const int g = k0 >> 7;
            const _Float16 s_h = (_Float16)sc[g * N_TOT + ncol];
            half2v sp; sp[0] = s_h; sp[1] = s_h;
            const unsigned zraw = qz[g * (N_TOT / 8) + (ncol >> 3)];
            const unsigned zn = (zraw >> ((ncol & 7) * 4)) & 15u;
            const half2v zp = __builtin_bit_cast(half2v, 0x64006400u | zn | (zn << 16));
            const int krow0 = k0 >> 3;
            #pragma unroll
            for (int i = 0; i < 4; ++i) {
                const int rr = b_rr + 2 * i;
                const unsigned raw = (unsigned)qw[(size_t)(krow0 + rr) * N_TOT + ncol];
                half8 w;
                #pragma unroll
                for (int p = 0; p < 4; ++p) {
                    const unsigned bits = ((raw >> (4 * p)) & 0x000F000Fu) | 0x64006400u;
                    half2v d = (__builtin_bit_cast(half2v, bits) - zp) * sp;
                    w[2 * p]     = d[0];
                    w[2 * p + 1] = d[1];
                }
                *(half8*)&Bs[b_n * LDK + rr * 8] = w;
            }
        }
        __syncthreads();
        #pragma unroll
        for (int kk = 0; kk < 2; ++kk) {
            half8 af[4], bf[4];
            #pragma unroll
            for (int i = 0; i < 4; ++i)
                af[i] = *(const half8*)&As[(wr * 64 + i * 16 + l16) * LDK + kk * 32 + quad * 8];
            #pragma unroll
            for (int j = 0; j < 4; ++j)
                bf[j] = *(const half8*)&Bs[(wc * 64 + j * 16 + l16) * LDK + kk * 32 + quad * 8];
            #pragma unroll
            for (int i = 0; i < 4; ++i)
                #pragma unroll
                for (int j = 0; j < 4; ++j)
                    acc[i][j] = __builtin_amdgcn_mfma_f32_16x16x32_f16(af[i], bf[j], acc[i][j], 0, 0, 0);
        }
    }

    float* o = out + (size_t)(m0 + wr * 64) * N_TOT + (n0 + wc * 64);
    #pragma unroll
    for (int i = 0; i < 4; ++i)
        #pragma unroll
        for (int j = 0; j < 4; ++j)
            #pragma unroll
            for (int r = 0; r < 4; ++r)
                o[(size_t)(i * 16 + quad * 4 + r) * N_TOT + (j * 16 + l16)] = acc[i][j][r];
}

extern "C" void kernel_launch(void* const* d_in, const int* in_sizes, int n_in,
                              void* d_out, int out_size, void* d_ws, size_t ws_size,
                              hipStream_t stream) {
    const float* x = (const float*)d_in[0];
    const int* qw = (const int*)d_in[1];
    const unsigned* qz = (const unsigned*)d_in[2];
    const float* sc = (const float*)d_in[3];
    float* out = (float*)d_out;

    const size_t a16_bytes = (size_t)M_TOT * K_TOT * 2;  // 67,108,864
    const size_t wt_bytes  = (size_t)N_TOT * K_TOT * 2;  // 90,177,536

    if (ws_size >= a16_bytes + wt_bytes) {
        _Float16* A16 = (_Float16*)d_ws;
        _Float16* Wt  = (_Float16*)((char*)d_ws + a16_bytes);
        cvt_x_fp16<<<dim3((M_TOT * K_TOT) / (256 * 8)), dim3(256), 0, stream>>>(x, A16);
        dequant_w<<<dim3(N_TOT / 256, (K_TOT / 8) / 4), dim3(256), 0, stream>>>(qw, qz, sc, Wt);
        gemm_f16<<<dim3(N_TOT / BN, M_TOT / BM), dim3(256), 0, stream>>>(A16, Wt, out);
    } else {
        gptq_fused_gemm<<<dim3(N_TOT / BN, M_TOT / BM), dim3(256), 0, stream>>>(x, qw, qz, sc, out);
    }
}

// Round 3
// 1481.041 us; speedup vs baseline: 1.0713x; 1.0713x over previous
//
#include <hip/hip_runtime.h>
#include <hip/hip_fp16.h>

// GPTQ int4 dequant + GEMM, decomposed (R3).
//
// R2 post-mortem: GEMM hit 608 TF == m233's 2-phase-with-conflict signature.
// Linear BK=64 LDS (128B rows, forced by global_load_lds) = 16-way bank
// conflict on every ds_read_b128: SQ_LDS_BANK_CONFLICT 2.7e8 = ~36% of cycles.
// Also dequant_w wrote 16B @ 8KB stride (uncoalesced, ~371us of prepass+misc).
//
// R3 changes:
//  1. T2 both-sides swizzle (rule #21): LDS stays linear; global SOURCE is
//     inverse-permuted per lane (slot ^= row&7), read address XORed the same
//     way. 3-bit XOR -> 2-way residue (free, m136).
//  2. T1 bijective XCD swizzle, 1D grid 5504 (5504%8==0): each XCD owns 8
//     contiguous m-rows -> A-panel L2 reuse.
//  3. dequant_w re-mapped: 8 lanes = 8 qw-rows of one n -> 128B contiguous
//     writes. Output stores nontemporal (352MB stream was evicting A/B).
//
// Numerics unchanged (bit-exact vs ref): nibble->fp16 bit trick, v_pk sub/mul.

#define M_TOT 8192
#define N_TOT 11008
#define K_TOT 4096

typedef _Float16 half2v __attribute__((ext_vector_type(2)));
typedef _Float16 half8 __attribute__((ext_vector_type(8)));
typedef float float4v __attribute__((ext_vector_type(4)));

// ---------------- prepass 1: x fp32 -> fp16 ----------------
__global__ __launch_bounds__(256) void cvt_x_fp16(const float* __restrict__ x,
                                                  _Float16* __restrict__ a16) {
    const size_t i = ((size_t)blockIdx.x * 256 + threadIdx.x) * 8;
    float4v v0 = *(const float4v*)(x + i);
    float4v v1 = *(const float4v*)(x + i + 4);
    half8 h;
    h[0] = (_Float16)v0[0]; h[1] = (_Float16)v0[1];
    h[2] = (_Float16)v0[2]; h[3] = (_Float16)v0[3];
    h[4] = (_Float16)v1[0]; h[5] = (_Float16)v1[1];
    h[6] = (_Float16)v1[2]; h[7] = (_Float16)v1[3];
    *(half8*)(a16 + i) = h;
}

// ---------------- prepass 2: qweight -> Wt[n][k] fp16 ----------------
// lane layout: n = bx*32 + tid/8, qw-row r = by*8 + tid&7.
// Writes: 8 lanes (same n, r consecutive) -> 128B contiguous. Fully coalesced.
// Reads: 4B strided (volume is only 22.5MB; L2 absorbs).
__global__ __launch_bounds__(256) void dequant_w(const int* __restrict__ qw,
                                                 const unsigned* __restrict__ qz,
                                                 const float* __restrict__ sc,
                                                 _Float16* __restrict__ wt) {
    const int tid = threadIdx.x;
    const int n = blockIdx.x * 32 + (tid >> 3);     // grid.x = 344
    const int r = blockIdx.y * 8 + (tid & 7);       // grid.y = 64 -> 512 rows
    const int g = r >> 4;                           // group = 8r/128
    const _Float16 s_h = (_Float16)sc[g * N_TOT + n];
    half2v sp; sp[0] = s_h; sp[1] = s_h;
    const unsigned zraw = qz[g * (N_TOT / 8) + (n >> 3)];
    const unsigned zn = (zraw >> ((n & 7) * 4)) & 15u;
    const half2v zp = __builtin_bit_cast(half2v, 0x64006400u | zn | (zn << 16));
    const unsigned raw = (unsigned)qw[(size_t)r * N_TOT + n];
    half8 w;
    #pragma unroll
    for (int p = 0; p < 4; ++p) {
        const unsigned bits = ((raw >> (4 * p)) & 0x000F000Fu) | 0x64006400u;
        half2v d = (__builtin_bit_cast(half2v, bits) - zp) * sp;  // v_pk, exact
        w[p]     = d[0];   // k = 8r + p
        w[p + 4] = d[1];   // k = 8r + p + 4
    }
    *(half8*)(wt + (size_t)n * K_TOT + r * 8) = w;
}

// ---------------- main GEMM: A16[M][K] x Wt[N][K]^T -> out[M][N] ----------------
#define BM 128
#define BN 128
#define BK 64
#define NBN (N_TOT / BN)   // 86
#define NBM (M_TOT / BM)   // 64
#define NWG (NBN * NBM)    // 5504, %8 == 0

__global__ __launch_bounds__(256) void gemm_f16(const _Float16* __restrict__ A,
                                                const _Float16* __restrict__ B,
                                                float* __restrict__ out) {
    __shared__ _Float16 As[BM * BK];  // 16 KB, linear (global_load_lds dest)
    __shared__ _Float16 Bs[BN * BK];  // 16 KB

    const int tid = threadIdx.x;

    // T1: bijective XCD swizzle. Each XCD gets 688 consecutive ids = 8 m-rows.
    const int flat = blockIdx.x;
    const int swz = (flat & 7) * (NWG / 8) + (flat >> 3);
    const int n0 = (swz % NBN) * BN;
    const int m0 = (swz / NBN) * BM;

    const int wave = tid >> 6;
    const int lane = tid & 63;
    const int wr = wave >> 1;         // wave row (m), 0..1
    const int wc = wave & 1;          // wave col (n), 0..1
    const int l16 = lane & 15;
    const int quad = lane >> 4;

    // Staging: wave w, issue i -> LDS rows i*32 + w*8 + lane/8 (linear dest,
    // HW adds lane*16B). Source column slot is inverse-swizzled: the lane
    // writing slot (lane&7) of a row with row&7 == lane>>3 fetches global
    // slot (lane&7) ^ (lane>>3). Read side XORs the same mask -> net identity.
    const int srow = wave * 8 + (lane >> 3);
    const int scol = ((lane & 7) ^ (lane >> 3)) * 8;   // halves

    // read-side XOR mask (halves): rows of af/bf have row&7 == l16&7
    const int ksw = (l16 & 7) * 8;

    float4v acc[4][4] = {};

    for (int k0 = 0; k0 < K_TOT; k0 += BK) {
        __syncthreads();  // protect LDS from previous iteration's reads
        #pragma unroll
        for (int i = 0; i < 4; ++i) {
            const _Float16* ga = A + (size_t)(m0 + i * 32 + srow) * K_TOT + k0 + scol;
            __builtin_amdgcn_global_load_lds(
                (const __attribute__((address_space(1))) void*)ga,
                (__attribute__((address_space(3))) void*)&As[(i * 32 + wave * 8) * BK],
                16, 0, 0);
            const _Float16* gb = B + (size_t)(n0 + i * 32 + srow) * K_TOT + k0 + scol;
            __builtin_amdgcn_global_load_lds(
                (const __attribute__((address_space(1))) void*)gb,
                (__attribute__((address_space(3))) void*)&Bs[(i * 32 + wave * 8) * BK],
                16, 0, 0);
        }
        __syncthreads();  // compiler drains vmcnt(0) before barrier

        #pragma unroll
        for (int kk = 0; kk < 2; ++kk) {
            half8 af[4], bf[4];
            #pragma unroll
            for (int i = 0; i < 4; ++i)  // A[m = wr*64+i*16+l16], k-slot swizzled
                af[i] = *(const half8*)&As[(wr * 64 + i * 16 + l16) * BK
                                           + ((kk * 32 + quad * 8) ^ ksw)];
            #pragma unroll
            for (int j = 0; j < 4; ++j)  // B[n = wc*64+j*16+l16]
                bf[j] = *(const half8*)&Bs[(wc * 64 + j * 16 + l16) * BK
                                           + ((kk * 32 + quad * 8) ^ ksw)];
            #pragma unroll
            for (int i = 0; i < 4; ++i)
                #pragma unroll
                for (int j = 0; j < 4; ++j)
                    acc[i][j] = __builtin_amdgcn_mfma_f32_16x16x32_f16(af[i], bf[j], acc[i][j], 0, 0, 0);
        }
    }

    // epilogue: C/D layout col = lane&15 (n), row = quad*4 + reg (m).
    // Nontemporal: output is write-once, keep it from evicting A/B in L2/L3.
    float* o = out + (size_t)(m0 + wr * 64) * N_TOT + (n0 + wc * 64);
    #pragma unroll
    for (int i = 0; i < 4; ++i)
        #pragma unroll
        for (int j = 0; j < 4; ++j)
            #pragma unroll
            for (int r = 0; r < 4; ++r)
                __builtin_nontemporal_store(acc[i][j][r],
                    &o[(size_t)(i * 16 + quad * 4 + r) * N_TOT + (j * 16 + l16)]);
}

// ---------------- fallback: fused kernel (R1, verified) ----------------
#define LDK 72

__global__ __launch_bounds__(256) void gptq_fused_gemm(
    const float* __restrict__ x,
    const int* __restrict__ qw,
    const unsigned* __restrict__ qz,
    const float* __restrict__ sc,
    float* __restrict__ out)
{
    __shared__ _Float16 As[BM * LDK];
    __shared__ _Float16 Bs[BN * LDK];

    const int tid = threadIdx.x;
    const int m0 = blockIdx.y * BM;
    const int n0 = blockIdx.x * BN;

    const int wave = tid >> 6;
    const int lane = tid & 63;
    const int wr = wave >> 1;
    const int wc = wave & 1;
    const int l16 = lane & 15;
    const int quad = lane >> 4;

    const int a_k8 = tid & 7;
    const int a_m  = tid >> 3;
    const int b_n  = tid & 127;
    const int b_rr = tid >> 7;
    const int ncol = n0 + b_n;

    float4v acc[4][4] = {};

    for (int k0 = 0; k0 < K_TOT; k0 += BK) {
        __syncthreads();
        {
            const float* src = x + (size_t)(m0 + a_m) * K_TOT + k0 + a_k8 * 8;
            #pragma unroll
            for (int i = 0; i < 4; ++i) {
                const float* p = src + (size_t)(i * 32) * K_TOT;
                float4v v0 = *(const float4v*)p;
                float4v v1 = *(const float4v*)(p + 4);
                half8 h;
                h[0] = (_Float16)v0[0]; h[1] = (_Float16)v1[0];
                h[2] = (_Float16)v0[1]; h[3] = (_Float16)v1[1];
                h[4] = (_Float16)v0[2]; h[5] = (_Float16)v1[2];
                h[6] = (_Float16)v0[3]; h[7] = (_Float16)v1[3];
                *(half8*)&As[(a_m + 32 * i) * LDK + a_k8 * 8] = h;
            }
        }
        {
            const int g = k0 >> 7;
            const _Float16 s_h = (_Float16)sc[g * N_TOT + ncol];
            half2v sp; sp[0] = s_h; sp[1] = s_h;
            const unsigned zraw = qz[g * (N_TOT / 8) + (ncol >> 3)];
            const unsigned zn = (zraw >> ((ncol & 7) * 4)) & 15u;
            const half2v zp = __builtin_bit_cast(half2v, 0x64006400u | zn | (zn << 16));
            const int krow0 = k0 >> 3;
            #pragma unroll
            for (int i = 0; i < 4; ++i) {
                const int rr = b_rr + 2 * i;
                const unsigned raw = (unsigned)qw[(size_t)(krow0 + rr) * N_TOT + ncol];
                half8 w;
                #pragma unroll
                for (int p = 0; p < 4; ++p) {
                    const unsigned bits = ((raw >> (4 * p)) & 0x000F000Fu) | 0x64006400u;
                    half2v d = (__builtin_bit_cast(half2v, bits) - zp) * sp;
                    w[2 * p]     = d[0];
                    w[2 * p + 1] = d[1];
                }
                *(half8*)&Bs[b_n * LDK + rr * 8] = w;
            }
        }
        __syncthreads();
        #pragma unroll
        for (int kk = 0; kk < 2; ++kk) {
            half8 af[4], bf[4];
            #pragma unroll
            for (int i = 0; i < 4; ++i)
                af[i] = *(const half8*)&As[(wr * 64 + i * 16 + l16) * LDK + kk * 32 + quad * 8];
            #pragma unroll
            for (int j = 0; j < 4; ++j)
                bf[j] = *(const half8*)&Bs[(wc * 64 + j * 16 + l16) * LDK + kk * 32 + quad * 8];
            #pragma unroll
            for (int i = 0; i < 4; ++i)
                #pragma unroll
                for (int j = 0; j < 4; ++j)
                    acc[i][j] = __builtin_amdgcn_mfma_f32_16x16x32_f16(af[i], bf[j], acc[i][j], 0, 0, 0);
        }
    }

    float* o = out + (size_t)(m0 + wr * 64) * N_TOT + (n0 + wc * 64);
    #pragma unroll
    for (int i = 0; i < 4; ++i)
        #pragma unroll
        for (int j = 0; j < 4; ++j)
            #pragma unroll
            for (int r = 0; r < 4; ++r)
                o[(size_t)(i * 16 + quad * 4 + r) * N_TOT + (j * 16 + l16)] = acc[i][j][r];
}

extern "C" void kernel_launch(void* const* d_in, const int* in_sizes, int n_in,
                              void* d_out, int out_size, void* d_ws, size_t ws_size,
                              hipStream_t stream) {
    const float* x = (const float*)d_in[0];
    const int* qw = (const int*)d_in[1];
    const unsigned* qz = (const unsigned*)d_in[2];
    const float* sc = (const float*)d_in[3];
    float* out = (float*)d_out;

    const size_t a16_bytes = (size_t)M_TOT * K_TOT * 2;  // 67,108,864
    const size_t wt_bytes  = (size_t)N_TOT * K_TOT * 2;  // 90,177,536

    if (ws_size >= a16_bytes + wt_bytes) {
        _Float16* A16 = (_Float16*)d_ws;
        _Float16* Wt  = (_Float16*)((char*)d_ws + a16_bytes);
        cvt_x_fp16<<<dim3((M_TOT * K_TOT) / (256 * 8)), dim3(256), 0, stream>>>(x, A16);
        dequant_w<<<dim3(N_TOT / 32, 512 / 8), dim3(256), 0, stream>>>(qw, qz, sc, Wt);
        gemm_f16<<<dim3(NWG), dim3(256), 0, stream>>>(A16, Wt, out);
    } else {
        gptq_fused_gemm<<<dim3(N_TOT / BN, M_TOT / BM), dim3(256), 0, stream>>>(x, qw, qz, sc, out);
    }
}

// Round 4
// 1225.365 us; speedup vs baseline: 1.2949x; 1.2087x over previous
//
#include <hip/hip_runtime.h>
#include <hip/hip_fp16.h>

// GPTQ int4 dequant + GEMM, decomposed (R4).
//
// R3 post-mortem: T2 swizzle killed bank conflicts (2.7e8 -> 0) but dur only
// -7%: the 2-phase stage->vmcnt(0)->barrier structure is the bottleneck
// (m233: ~72% overhead; 2ph ceiling 607-682 TF; we measured 655).
// Nontemporal stores inflated WRITE_SIZE 352->499MB -> reverted.
//
// R4: deep-pipelined GEMM (T3+T4+T5), plain-HIP port of the 8-phase template:
//   256x256 tile, BK=32, 4 LDS buffers (128 KiB), 8 waves (2M x 4N),
//   2 phases/K-tile: {ds_read frags | stage 2 global_load_lds for tile s+3 |
//   raw s_barrier | setprio(1) 16 MFMA setprio(0) | barrier}.
//   Counted vmcnt(8) ONCE per K-tile (keeps tiles s+2,s+3 in flight,
//   guarantees s+1 landed == the exact read deadline). Tail: vmcnt(4)/(0).
//   Safety: stages write buf[(s+3)&3], last read at step s-1 (>=2 barriers
//   back); per-phase barriers cap wave skew << hazard distance; all ds_reads
//   feed MFMAs before the trailing barrier (lgkm-waited), so no read is
//   outstanding when a later stage lands.
// T1: bijective XCD swizzle (1376 blocks, %8==0). T2: slot^=(row&3) both-sides
// swizzle (verified 0 conflicts in R3 at the 8-slot variant).
//
// Prepasses (unchanged, bit-exact): x fp32->fp16 RTE; qweight nibble->fp16 via
// (raw>>4p & 0x000F000F)|0x64006400, v_pk sub/mul.

#define M_TOT 8192
#define N_TOT 11008
#define K_TOT 4096

typedef _Float16 half2v __attribute__((ext_vector_type(2)));
typedef _Float16 half8 __attribute__((ext_vector_type(8)));
typedef float float4v __attribute__((ext_vector_type(4)));

// ---------------- prepass 1: x fp32 -> fp16 ----------------
__global__ __launch_bounds__(256) void cvt_x_fp16(const float* __restrict__ x,
                                                  _Float16* __restrict__ a16) {
    const size_t i = ((size_t)blockIdx.x * 256 + threadIdx.x) * 8;
    float4v v0 = *(const float4v*)(x + i);
    float4v v1 = *(const float4v*)(x + i + 4);
    half8 h;
    h[0] = (_Float16)v0[0]; h[1] = (_Float16)v0[1];
    h[2] = (_Float16)v0[2]; h[3] = (_Float16)v0[3];
    h[4] = (_Float16)v1[0]; h[5] = (_Float16)v1[1];
    h[6] = (_Float16)v1[2]; h[7] = (_Float16)v1[3];
    *(half8*)(a16 + i) = h;
}

// ---------------- prepass 2: qweight -> Wt[n][k] fp16 ----------------
__global__ __launch_bounds__(256) void dequant_w(const int* __restrict__ qw,
                                                 const unsigned* __restrict__ qz,
                                                 const float* __restrict__ sc,
                                                 _Float16* __restrict__ wt) {
    const int tid = threadIdx.x;
    const int n = blockIdx.x * 32 + (tid >> 3);     // grid.x = 344
    const int r = blockIdx.y * 8 + (tid & 7);       // grid.y = 64 -> 512 rows
    const int g = r >> 4;                           // group = 8r/128
    const _Float16 s_h = (_Float16)sc[g * N_TOT + n];
    half2v sp; sp[0] = s_h; sp[1] = s_h;
    const unsigned zraw = qz[g * (N_TOT / 8) + (n >> 3)];
    const unsigned zn = (zraw >> ((n & 7) * 4)) & 15u;
    const half2v zp = __builtin_bit_cast(half2v, 0x64006400u | zn | (zn << 16));
    const unsigned raw = (unsigned)qw[(size_t)r * N_TOT + n];
    half8 w;
    #pragma unroll
    for (int p = 0; p < 4; ++p) {
        const unsigned bits = ((raw >> (4 * p)) & 0x000F000Fu) | 0x64006400u;
        half2v d = (__builtin_bit_cast(half2v, bits) - zp) * sp;  // v_pk, exact
        w[p]     = d[0];   // k = 8r + p
        w[p + 4] = d[1];   // k = 8r + p + 4
    }
    *(half8*)(wt + (size_t)n * K_TOT + r * 8) = w;
}

// ---------------- main GEMM: 256x256 tile, 4-buffer deep pipeline ----------------
#define TBM 256
#define TBN 256
#define TBK 32
#define NKT (K_TOT / TBK)          // 128 K-tiles
#define TNBN (N_TOT / TBN)         // 43
#define TNBM (M_TOT / TBM)         // 32
#define TNWG (TNBN * TNBM)         // 1376, %8 == 0

__global__ __launch_bounds__(512, 2) void gemm_f16_8p(const _Float16* __restrict__ A,
                                                      const _Float16* __restrict__ B,
                                                      float* __restrict__ out) {
    // 4 buffers x 256 rows x 32 halves = 16 KB each matrix-buffer; total 128 KiB
    __shared__ _Float16 As[4 * 256 * 32];
    __shared__ _Float16 Bs[4 * 256 * 32];

    const int tid = threadIdx.x;
    const int wave = tid >> 6;
    const int lane = tid & 63;

    // T1: bijective XCD swizzle (1376 % 8 == 0)
    const int flat = blockIdx.x;
    const int swz = (flat & 7) * (TNWG / 8) + (flat >> 3);
    const int n0 = (swz % TNBN) * TBN;
    const int m0 = (swz / TNBN) * TBM;

    const int wm = wave >> 2;         // 0..1 (m half, 128 rows)
    const int wn = wave & 3;          // 0..3 (n quarter, 64 cols)
    const int l16 = lane & 15;
    const int quad = lane >> 4;

    // ---- staging geometry: one issue = 512 thr x 16B = 8 KB = 128 rows x 64B
    // LDS dest (linear): wave*1024B (+ lane*16 by HW) -> row = wave*16 + lane/4,
    // slot_lin = lane&3. Source k-slot inverse-swizzled: slot_lin ^ (row&3).
    const int s_row  = wave * 16 + (lane >> 2);                 // 0..127
    const int s_slot = ((lane & 3) ^ ((lane >> 2) & 3)) * 8;    // halves
    const _Float16* a_src = A + (size_t)(m0 + s_row) * K_TOT + s_slot;
    const _Float16* b_src = B + (size_t)(n0 + s_row) * K_TOT + s_slot;
    const int s_dst = wave * 512;     // halves within an 8 KB issue block

    // ---- read-side swizzle: LDS slot (quad ^ (row&3)) holds global k-group quad
    const int rd_off = (quad ^ (l16 & 3)) * 8;   // row&3 == l16&3 (bases %16==0)

    #define STAGE_A(t) do {                                                      \
        const int b_ = (t) & 3;                                                  \
        const _Float16* s0_ = a_src + (size_t)(t) * TBK;                         \
        __builtin_amdgcn_global_load_lds(                                        \
            (const __attribute__((address_space(1))) void*)s0_,                  \
            (__attribute__((address_space(3))) void*)&As[b_ * 8192 + s_dst],     \
            16, 0, 0);                                                           \
        __builtin_amdgcn_global_load_lds(                                        \
            (const __attribute__((address_space(1))) void*)(s0_ + (size_t)128 * K_TOT), \
            (__attribute__((address_space(3))) void*)&As[b_ * 8192 + 4096 + s_dst],     \
            16, 0, 0);                                                           \
    } while (0)

    #define STAGE_B(t) do {                                                      \
        const int b_ = (t) & 3;                                                  \
        const _Float16* s0_ = b_src + (size_t)(t) * TBK;                         \
        __builtin_amdgcn_global_load_lds(                                        \
            (const __attribute__((address_space(1))) void*)s0_,                  \
            (__attribute__((address_space(3))) void*)&Bs[b_ * 8192 + s_dst],     \
            16, 0, 0);                                                           \
        __builtin_amdgcn_global_load_lds(                                        \
            (const __attribute__((address_space(1))) void*)(s0_ + (size_t)128 * K_TOT), \
            (__attribute__((address_space(3))) void*)&Bs[b_ * 8192 + 4096 + s_dst],     \
            16, 0, 0);                                                           \
    } while (0)

    float4v acc[8][4] = {};

    // ---- prologue: stage tiles 0,1,2 (12 issues); wait tile 0 (newest 8 = 1,2)
    STAGE_A(0); STAGE_B(0);
    STAGE_A(1); STAGE_B(1);
    STAGE_A(2); STAGE_B(2);
    asm volatile("s_waitcnt vmcnt(8)" ::: "memory");
    __builtin_amdgcn_s_barrier();

    // ---- main loop: one K-tile per step, 2 phases/step
    #define STEP(s, DO_STAGE, WAIT_STMT) do {                                    \
        const int b = (s) & 3;                                                   \
        const _Float16* Ab = &As[b * 8192];                                      \
        const _Float16* Bb = &Bs[b * 8192];                                      \
        half8 af[4], bf[4];                                                      \
        /* P1: af half 0 (4) + bf all (4) = 8 ds_read_b128 */                    \
        _Pragma("unroll")                                                        \
        for (int i = 0; i < 4; ++i)                                              \
            af[i] = *(const half8*)&Ab[(wm * 128 + i * 16 + l16) * TBK + rd_off];\
        _Pragma("unroll")                                                        \
        for (int j = 0; j < 4; ++j)                                              \
            bf[j] = *(const half8*)&Bb[(wn * 64 + j * 16 + l16) * TBK + rd_off]; \
        if (DO_STAGE) STAGE_A((s) + 3);                                          \
        __builtin_amdgcn_s_barrier();                                            \
        __builtin_amdgcn_s_setprio(1);                                           \
        _Pragma("unroll")                                                        \
        for (int i = 0; i < 4; ++i)                                              \
            _Pragma("unroll")                                                    \
            for (int j = 0; j < 4; ++j)                                          \
                acc[i][j] = __builtin_amdgcn_mfma_f32_16x16x32_f16(af[i], bf[j], acc[i][j], 0, 0, 0); \
        __builtin_amdgcn_s_setprio(0);                                           \
        __builtin_amdgcn_s_barrier();                                            \
        /* P2: af half 1 (4 ds_read), bf resident */                             \
        _Pragma("unroll")                                                        \
        for (int i = 0; i < 4; ++i)                                              \
            af[i] = *(const half8*)&Ab[(wm * 128 + 64 + i * 16 + l16) * TBK + rd_off]; \
        if (DO_STAGE) STAGE_B((s) + 3);                                          \
        __builtin_amdgcn_s_barrier();                                            \
        __builtin_amdgcn_s_setprio(1);                                           \
        _Pragma("unroll")                                                        \
        for (int i = 0; i < 4; ++i)                                              \
            _Pragma("unroll")                                                    \
            for (int j = 0; j < 4; ++j)                                          \
                acc[4 + i][j] = __builtin_amdgcn_mfma_f32_16x16x32_f16(af[i], bf[j], acc[4 + i][j], 0, 0, 0); \
        __builtin_amdgcn_s_setprio(0);                                           \
        WAIT_STMT;                                                               \
        __builtin_amdgcn_s_barrier();                                            \
    } while (0)

    for (int s = 0; s < NKT - 3; ++s)   // s = 0..124: stage tile s+3, vmcnt(8)
        STEP(s, 1, asm volatile("s_waitcnt vmcnt(8)" ::: "memory"));
    STEP(NKT - 3, 0, asm volatile("s_waitcnt vmcnt(4)" ::: "memory"));  // s=125
    STEP(NKT - 2, 0, asm volatile("s_waitcnt vmcnt(0)" ::: "memory"));  // s=126
    STEP(NKT - 1, 0, (void)0);                                          // s=127

    #undef STEP
    #undef STAGE_A
    #undef STAGE_B

    // ---- epilogue: C/D layout col = l16 (n), row = quad*4 + r (m)
    float* o = out + (size_t)(m0 + wm * 128) * N_TOT + (n0 + wn * 64);
    #pragma unroll
    for (int mf = 0; mf < 8; ++mf)
        #pragma unroll
        for (int j = 0; j < 4; ++j)
            #pragma unroll
            for (int r = 0; r < 4; ++r)
                o[(size_t)(mf * 16 + quad * 4 + r) * N_TOT + (j * 16 + l16)] = acc[mf][j][r];
}

// ---------------- fallback: fused kernel (R1, verified) ----------------
#define BM 128
#define BN 128
#define BK 64
#define LDK 72

__global__ __launch_bounds__(256) void gptq_fused_gemm(
    const float* __restrict__ x,
    const int* __restrict__ qw,
    const unsigned* __restrict__ qz,
    const float* __restrict__ sc,
    float* __restrict__ out)
{
    __shared__ _Float16 As[BM * LDK];
    __shared__ _Float16 Bs[BN * LDK];

    const int tid = threadIdx.x;
    const int m0 = blockIdx.y * BM;
    const int n0 = blockIdx.x * BN;

    const int wave = tid >> 6;
    const int lane = tid & 63;
    const int wr = wave >> 1;
    const int wc = wave & 1;
    const int l16 = lane & 15;
    const int quad = lane >> 4;

    const int a_k8 = tid & 7;
    const int a_m  = tid >> 3;
    const int b_n  = tid & 127;
    const int b_rr = tid >> 7;
    const int ncol = n0 + b_n;

    float4v acc[4][4] = {};

    for (int k0 = 0; k0 < K_TOT; k0 += BK) {
        __syncthreads();
        {
            const float* src = x + (size_t)(m0 + a_m) * K_TOT + k0 + a_k8 * 8;
            #pragma unroll
            for (int i = 0; i < 4; ++i) {
                const float* p = src + (size_t)(i * 32) * K_TOT;
                float4v v0 = *(const float4v*)p;
                float4v v1 = *(const float4v*)(p + 4);
                half8 h;
                h[0] = (_Float16)v0[0]; h[1] = (_Float16)v1[0];
                h[2] = (_Float16)v0[1]; h[3] = (_Float16)v1[1];
                h[4] = (_Float16)v0[2]; h[5] = (_Float16)v1[2];
                h[6] = (_Float16)v0[3]; h[7] = (_Float16)v1[3];
                *(half8*)&As[(a_m + 32 * i) * LDK + a_k8 * 8] = h;
            }
        }
        {
            const int g = k0 >> 7;
            const _Float16 s_h = (_Float16)sc[g * N_TOT + ncol];
            half2v sp; sp[0] = s_h; sp[1] = s_h;
            const unsigned zraw = qz[g * (N_TOT / 8) + (ncol >> 3)];
            const unsigned zn = (zraw >> ((ncol & 7) * 4)) & 15u;
            const half2v zp = __builtin_bit_cast(half2v, 0x64006400u | zn | (zn << 16));
            const int krow0 = k0 >> 3;
            #pragma unroll
            for (int i = 0; i < 4; ++i) {
                const int rr = b_rr + 2 * i;
                const unsigned raw = (unsigned)qw[(size_t)(krow0 + rr) * N_TOT + ncol];
                half8 w;
                #pragma unroll
                for (int p = 0; p < 4; ++p) {
                    const unsigned bits = ((raw >> (4 * p)) & 0x000F000Fu) | 0x64006400u;
                    half2v d = (__builtin_bit_cast(half2v, bits) - zp) * sp;
                    w[2 * p]     = d[0];
                    w[2 * p + 1] = d[1];
                }
                *(half8*)&Bs[b_n * LDK + rr * 8] = w;
            }
        }
        __syncthreads();
        #pragma unroll
        for (int kk = 0; kk < 2; ++kk) {
            half8 af[4], bf[4];
            #pragma unroll
            for (int i = 0; i < 4; ++i)
                af[i] = *(const half8*)&As[(wr * 64 + i * 16 + l16) * LDK + kk * 32 + quad * 8];
            #pragma unroll
            for (int j = 0; j < 4; ++j)
                bf[j] = *(const half8*)&Bs[(wc * 64 + j * 16 + l16) * LDK + kk * 32 + quad * 8];
            #pragma unroll
            for (int i = 0; i < 4; ++i)
                #pragma unroll
                for (int j = 0; j < 4; ++j)
                    acc[i][j] = __builtin_amdgcn_mfma_f32_16x16x32_f16(af[i], bf[j], acc[i][j], 0, 0, 0);
        }
    }

    float* o = out + (size_t)(m0 + wr * 64) * N_TOT + (n0 + wc * 64);
    #pragma unroll
    for (int i = 0; i < 4; ++i)
        #pragma unroll
        for (int j = 0; j < 4; ++j)
            #pragma unroll
            for (int r = 0; r < 4; ++r)
                o[(size_t)(i * 16 + quad * 4 + r) * N_TOT + (j * 16 + l16)] = acc[i][j][r];
}

extern "C" void kernel_launch(void* const* d_in, const int* in_sizes, int n_in,
                              void* d_out, int out_size, void* d_ws, size_t ws_size,
                              hipStream_t stream) {
    const float* x = (const float*)d_in[0];
    const int* qw = (const int*)d_in[1];
    const unsigned* qz = (const unsigned*)d_in[2];
    const float* sc = (const float*)d_in[3];
    float* out = (float*)d_out;

    const size_t a16_bytes = (size_t)M_TOT * K_TOT * 2;  // 67,108,864
    const size_t wt_bytes  = (size_t)N_TOT * K_TOT * 2;  // 90,177,536

    if (ws_size >= a16_bytes + wt_bytes) {
        _Float16* A16 = (_Float16*)d_ws;
        _Float16* Wt  = (_Float16*)((char*)d_ws + a16_bytes);
        cvt_x_fp16<<<dim3((M_TOT * K_TOT) / (256 * 8)), dim3(256), 0, stream>>>(x, A16);
        dequant_w<<<dim3(N_TOT / 32, 512 / 8), dim3(256), 0, stream>>>(qw, qz, sc, Wt);
        gemm_f16_8p<<<dim3(TNWG), dim3(512), 0, stream>>>(A16, Wt, out);
    } else {
        gptq_fused_gemm<<<dim3(N_TOT / BN, M_TOT / BM), dim3(256), 0, stream>>>(x, qw, qz, sc, out);
    }
}

// Round 5
// 1224.047 us; speedup vs baseline: 1.2963x; 1.0011x over previous
//
#include <hip/hip_runtime.h>
#include <hip/hip_fp16.h>

// GPTQ int4 dequant + GEMM, decomposed (R5).
//
// R4 post-mortem: deep global->LDS pipeline got 840 TF (MfmaUtil 37%), but each
// phase still did {ds_read burst -> lgkm -> MFMA} serially in-wave: ~2000 of
// 3069 cyc/step were exposed LDS-read latency + barrier sync (4 barriers/step).
//
// R5: register-fragment pipelining. MFMA consumes frags read in the PREVIOUS
// phase; each read burst issues right after an MFMA cluster (latency hides
// under matrix pipe + barrier). One barrier per K-step (was 4) -- safe because
// during step s no wave reads buf[s-1] (reads are for buf[s]/buf[s+1]), and
// all buf[s-1] reads were lgkm-consumed before the step-(s-1) barrier.
// vmcnt(4) per step: end of step s guarantees tile s+2 (prefetched during
// step s+1). Prologue vmcnt(4) = tiles 0,1. Tail: vmcnt(0) at s=NKT-3.
//
// Prepasses (unchanged, bit-exact): x fp32->fp16 RTE; qweight nibble->fp16 via
// (raw>>4p & 0x000F000F)|0x64006400, v_pk sub/mul.

#define M_TOT 8192
#define N_TOT 11008
#define K_TOT 4096

typedef _Float16 half2v __attribute__((ext_vector_type(2)));
typedef _Float16 half8 __attribute__((ext_vector_type(8)));
typedef float float4v __attribute__((ext_vector_type(4)));

// ---------------- prepass 1: x fp32 -> fp16 ----------------
__global__ __launch_bounds__(256) void cvt_x_fp16(const float* __restrict__ x,
                                                  _Float16* __restrict__ a16) {
    const size_t i = ((size_t)blockIdx.x * 256 + threadIdx.x) * 8;
    float4v v0 = *(const float4v*)(x + i);
    float4v v1 = *(const float4v*)(x + i + 4);
    half8 h;
    h[0] = (_Float16)v0[0]; h[1] = (_Float16)v0[1];
    h[2] = (_Float16)v0[2]; h[3] = (_Float16)v0[3];
    h[4] = (_Float16)v1[0]; h[5] = (_Float16)v1[1];
    h[6] = (_Float16)v1[2]; h[7] = (_Float16)v1[3];
    *(half8*)(a16 + i) = h;
}

// ---------------- prepass 2: qweight -> Wt[n][k] fp16 ----------------
__global__ __launch_bounds__(256) void dequant_w(const int* __restrict__ qw,
                                                 const unsigned* __restrict__ qz,
                                                 const float* __restrict__ sc,
                                                 _Float16* __restrict__ wt) {
    const int tid = threadIdx.x;
    const int n = blockIdx.x * 32 + (tid >> 3);     // grid.x = 344
    const int r = blockIdx.y * 8 + (tid & 7);       // grid.y = 64 -> 512 rows
    const int g = r >> 4;                           // group = 8r/128
    const _Float16 s_h = (_Float16)sc[g * N_TOT + n];
    half2v sp; sp[0] = s_h; sp[1] = s_h;
    const unsigned zraw = qz[g * (N_TOT / 8) + (n >> 3)];
    const unsigned zn = (zraw >> ((n & 7) * 4)) & 15u;
    const half2v zp = __builtin_bit_cast(half2v, 0x64006400u | zn | (zn << 16));
    const unsigned raw = (unsigned)qw[(size_t)r * N_TOT + n];
    half8 w;
    #pragma unroll
    for (int p = 0; p < 4; ++p) {
        const unsigned bits = ((raw >> (4 * p)) & 0x000F000Fu) | 0x64006400u;
        half2v d = (__builtin_bit_cast(half2v, bits) - zp) * sp;  // v_pk, exact
        w[p]     = d[0];   // k = 8r + p
        w[p + 4] = d[1];   // k = 8r + p + 4
    }
    *(half8*)(wt + (size_t)n * K_TOT + r * 8) = w;
}

// ---------------- main GEMM: 256x256 tile, 4-buffer, reg-pipelined ----------------
#define TBM 256
#define TBN 256
#define TBK 32
#define NKT (K_TOT / TBK)          // 128 K-tiles
#define TNBN (N_TOT / TBN)         // 43
#define TNBM (M_TOT / TBM)         // 32
#define TNWG (TNBN * TNBM)         // 1376, %8 == 0

__global__ __launch_bounds__(512, 2) void gemm_f16_pl(const _Float16* __restrict__ A,
                                                      const _Float16* __restrict__ B,
                                                      float* __restrict__ out) {
    __shared__ _Float16 As[4 * 256 * 32];  // 64 KiB
    __shared__ _Float16 Bs[4 * 256 * 32];  // 64 KiB

    const int tid = threadIdx.x;
    const int wave = tid >> 6;
    const int lane = tid & 63;

    // T1: bijective XCD swizzle (1376 % 8 == 0)
    const int flat = blockIdx.x;
    const int swz = (flat & 7) * (TNWG / 8) + (flat >> 3);
    const int n0 = (swz % TNBN) * TBN;
    const int m0 = (swz / TNBN) * TBM;

    const int wm = wave >> 2;         // 0..1 (m half, 128 rows)
    const int wn = wave & 3;          // 0..3 (n quarter, 64 cols)
    const int l16 = lane & 15;
    const int quad = lane >> 4;

    // staging: one issue = 512 thr x 16B = 8 KB = 128 rows x 64B (linear dest).
    // row = wave*16 + lane/4, slot = lane&3; source k-slot inverse-swizzled.
    const int s_row  = wave * 16 + (lane >> 2);                 // 0..127
    const int s_slot = ((lane & 3) ^ ((lane >> 2) & 3)) * 8;    // halves
    const _Float16* a_src = A + (size_t)(m0 + s_row) * K_TOT + s_slot;
    const _Float16* b_src = B + (size_t)(n0 + s_row) * K_TOT + s_slot;
    const int s_dst = wave * 512;     // halves within an 8 KB issue block

    // read-side swizzle: LDS slot (quad ^ (row&3)) holds global k-group quad
    const int rd_off = (quad ^ (l16 & 3)) * 8;   // row&3 == l16&3 (bases %16==0)

    #define STAGE_A(t) do {                                                      \
        const int b_ = (t) & 3;                                                  \
        const _Float16* s0_ = a_src + (size_t)(t) * TBK;                         \
        __builtin_amdgcn_global_load_lds(                                        \
            (const __attribute__((address_space(1))) void*)s0_,                  \
            (__attribute__((address_space(3))) void*)&As[b_ * 8192 + s_dst],     \
            16, 0, 0);                                                           \
        __builtin_amdgcn_global_load_lds(                                        \
            (const __attribute__((address_space(1))) void*)(s0_ + (size_t)128 * K_TOT), \
            (__attribute__((address_space(3))) void*)&As[b_ * 8192 + 4096 + s_dst],     \
            16, 0, 0);                                                           \
    } while (0)

    #define STAGE_B(t) do {                                                      \
        const int b_ = (t) & 3;                                                  \
        const _Float16* s0_ = b_src + (size_t)(t) * TBK;                         \
        __builtin_amdgcn_global_load_lds(                                        \
            (const __attribute__((address_space(1))) void*)s0_,                  \
            (__attribute__((address_space(3))) void*)&Bs[b_ * 8192 + s_dst],     \
            16, 0, 0);                                                           \
        __builtin_amdgcn_global_load_lds(                                        \
            (const __attribute__((address_space(1))) void*)(s0_ + (size_t)128 * K_TOT), \
            (__attribute__((address_space(3))) void*)&Bs[b_ * 8192 + 4096 + s_dst],     \
            16, 0, 0);                                                           \
    } while (0)

    half8 af0[4], af1[4], bf[4];          // loop-carried fragment registers
    float4v acc0[4][4] = {};              // m-half 0 accumulators
    float4v acc1[4][4] = {};              // m-half 1 accumulators

    // ---- prologue: stage tiles 0,1,2; vmcnt(4) -> tiles 0,1 landed
    STAGE_A(0); STAGE_B(0);
    STAGE_A(1); STAGE_B(1);
    STAGE_A(2); STAGE_B(2);
    asm volatile("s_waitcnt vmcnt(4)" ::: "memory");
    __builtin_amdgcn_s_barrier();

    // preload frags for step 0 (af half 0 + bf from buf 0)
    #pragma unroll
    for (int i = 0; i < 4; ++i)
        af0[i] = *(const half8*)&As[(wm * 128 + i * 16 + l16) * TBK + rd_off];
    #pragma unroll
    for (int j = 0; j < 4; ++j)
        bf[j] = *(const half8*)&Bs[(wn * 64 + j * 16 + l16) * TBK + rd_off];

    // ---- main loop: 1 barrier per K-step; MFMA consumes prev-phase reads
    #define STEP(s, DO_STAGE, DO_PREFETCH, WAIT_STMT) do {                       \
        const int cur = (s) & 3;                                                 \
        const int nxt = ((s) + 1) & 3;                                           \
        const _Float16* Ac = &As[cur * 8192];                                    \
        const _Float16* An = &As[nxt * 8192];                                    \
        const _Float16* Bn = &Bs[nxt * 8192];                                    \
        /* read af half 1 early: latency hides under acc0 MFMA cluster */        \
        _Pragma("unroll")                                                        \
        for (int i = 0; i < 4; ++i)                                              \
            af1[i] = *(const half8*)&Ac[(wm * 128 + 64 + i * 16 + l16) * TBK + rd_off]; \
        if (DO_STAGE) STAGE_A((s) + 3);                                          \
        __builtin_amdgcn_s_setprio(1);                                           \
        _Pragma("unroll")                                                        \
        for (int i = 0; i < 4; ++i)                                              \
            _Pragma("unroll")                                                    \
            for (int j = 0; j < 4; ++j)                                          \
                acc0[i][j] = __builtin_amdgcn_mfma_f32_16x16x32_f16(af0[i], bf[j], acc0[i][j], 0, 0, 0); \
        __builtin_amdgcn_s_setprio(0);                                           \
        if (DO_STAGE) STAGE_B((s) + 3);                                          \
        __builtin_amdgcn_s_setprio(1);                                           \
        _Pragma("unroll")                                                        \
        for (int i = 0; i < 4; ++i)                                              \
            _Pragma("unroll")                                                    \
            for (int j = 0; j < 4; ++j)                                          \
                acc1[i][j] = __builtin_amdgcn_mfma_f32_16x16x32_f16(af1[i], bf[j], acc1[i][j], 0, 0, 0); \
        __builtin_amdgcn_s_setprio(0);                                           \
        /* prefetch next step's af half 0 + bf: hides under barrier + next acc0 */ \
        if (DO_PREFETCH) {                                                       \
            _Pragma("unroll")                                                    \
            for (int i = 0; i < 4; ++i)                                          \
                af0[i] = *(const half8*)&An[(wm * 128 + i * 16 + l16) * TBK + rd_off]; \
            _Pragma("unroll")                                                    \
            for (int j = 0; j < 4; ++j)                                          \
                bf[j] = *(const half8*)&Bn[(wn * 64 + j * 16 + l16) * TBK + rd_off];   \
        }                                                                        \
        WAIT_STMT;                                                               \
        __builtin_amdgcn_s_barrier();                                            \
    } while (0)

    for (int s = 0; s < NKT - 3; ++s)   // s = 0..124: stage s+3, vmcnt(4)
        STEP(s, 1, 1, asm volatile("s_waitcnt vmcnt(4)" ::: "memory"));
    STEP(NKT - 3, 0, 1, asm volatile("s_waitcnt vmcnt(0)" ::: "memory"));  // 125
    STEP(NKT - 2, 0, 1, (void)0);                                          // 126
    STEP(NKT - 1, 0, 0, (void)0);                                          // 127

    #undef STEP
    #undef STAGE_A
    #undef STAGE_B

    // ---- epilogue: C/D layout col = l16 (n), row = quad*4 + r (m)
    float* o = out + (size_t)(m0 + wm * 128) * N_TOT + (n0 + wn * 64);
    #pragma unroll
    for (int i = 0; i < 4; ++i)
        #pragma unroll
        for (int j = 0; j < 4; ++j)
            #pragma unroll
            for (int r = 0; r < 4; ++r) {
                o[(size_t)(i * 16 + quad * 4 + r) * N_TOT + (j * 16 + l16)] = acc0[i][j][r];
                o[(size_t)(64 + i * 16 + quad * 4 + r) * N_TOT + (j * 16 + l16)] = acc1[i][j][r];
            }
}

// ---------------- fallback: fused kernel (R1, verified) ----------------
#define BM 128
#define BN 128
#define BK 64
#define LDK 72

__global__ __launch_bounds__(256) void gptq_fused_gemm(
    const float* __restrict__ x,
    const int* __restrict__ qw,
    const unsigned* __restrict__ qz,
    const float* __restrict__ sc,
    float* __restrict__ out)
{
    __shared__ _Float16 As[BM * LDK];
    __shared__ _Float16 Bs[BN * LDK];

    const int tid = threadIdx.x;
    const int m0 = blockIdx.y * BM;
    const int n0 = blockIdx.x * BN;

    const int wave = tid >> 6;
    const int lane = tid & 63;
    const int wr = wave >> 1;
    const int wc = wave & 1;
    const int l16 = lane & 15;
    const int quad = lane >> 4;

    const int a_k8 = tid & 7;
    const int a_m  = tid >> 3;
    const int b_n  = tid & 127;
    const int b_rr = tid >> 7;
    const int ncol = n0 + b_n;

    float4v acc[4][4] = {};

    for (int k0 = 0; k0 < K_TOT; k0 += BK) {
        __syncthreads();
        {
            const float* src = x + (size_t)(m0 + a_m) * K_TOT + k0 + a_k8 * 8;
            #pragma unroll
            for (int i = 0; i < 4; ++i) {
                const float* p = src + (size_t)(i * 32) * K_TOT;
                float4v v0 = *(const float4v*)p;
                float4v v1 = *(const float4v*)(p + 4);
                half8 h;
                h[0] = (_Float16)v0[0]; h[1] = (_Float16)v1[0];
                h[2] = (_Float16)v0[1]; h[3] = (_Float16)v1[1];
                h[4] = (_Float16)v0[2]; h[5] = (_Float16)v1[2];
                h[6] = (_Float16)v0[3]; h[7] = (_Float16)v1[3];
                *(half8*)&As[(a_m + 32 * i) * LDK + a_k8 * 8] = h;
            }
        }
        {
            const int g = k0 >> 7;
            const _Float16 s_h = (_Float16)sc[g * N_TOT + ncol];
            half2v sp; sp[0] = s_h; sp[1] = s_h;
            const unsigned zraw = qz[g * (N_TOT / 8) + (ncol >> 3)];
            const unsigned zn = (zraw >> ((ncol & 7) * 4)) & 15u;
            const half2v zp = __builtin_bit_cast(half2v, 0x64006400u | zn | (zn << 16));
            const int krow0 = k0 >> 3;
            #pragma unroll
            for (int i = 0; i < 4; ++i) {
                const int rr = b_rr + 2 * i;
                const unsigned raw = (unsigned)qw[(size_t)(krow0 + rr) * N_TOT + ncol];
                half8 w;
                #pragma unroll
                for (int p = 0; p < 4; ++p) {
                    const unsigned bits = ((raw >> (4 * p)) & 0x000F000Fu) | 0x64006400u;
                    half2v d = (__builtin_bit_cast(half2v, bits) - zp) * sp;
                    w[2 * p]     = d[0];
                    w[2 * p + 1] = d[1];
                }
                *(half8*)&Bs[b_n * LDK + rr * 8] = w;
            }
        }
        __syncthreads();
        #pragma unroll
        for (int kk = 0; kk < 2; ++kk) {
            half8 af[4], bf[4];
            #pragma unroll
            for (int i = 0; i < 4; ++i)
                af[i] = *(const half8*)&As[(wr * 64 + i * 16 + l16) * LDK + kk * 32 + quad * 8];
            #pragma unroll
            for (int j = 0; j < 4; ++j)
                bf[j] = *(const half8*)&Bs[(wc * 64 + j * 16 + l16) * LDK + kk * 32 + quad * 8];
            #pragma unroll
            for (int i = 0; i < 4; ++i)
                #pragma unroll
                for (int j = 0; j < 4; ++j)
                    acc[i][j] = __builtin_amdgcn_mfma_f32_16x16x32_f16(af[i], bf[j], acc[i][j], 0, 0, 0);
        }
    }

    float* o = out + (size_t)(m0 + wr * 64) * N_TOT + (n0 + wc * 64);
    #pragma unroll
    for (int i = 0; i < 4; ++i)
        #pragma unroll
        for (int j = 0; j < 4; ++j)
            #pragma unroll
            for (int r = 0; r < 4; ++r)
                o[(size_t)(i * 16 + quad * 4 + r) * N_TOT + (j * 16 + l16)] = acc[i][j][r];
}

extern "C" void kernel_launch(void* const* d_in, const int* in_sizes, int n_in,
                              void* d_out, int out_size, void* d_ws, size_t ws_size,
                              hipStream_t stream) {
    const float* x = (const float*)d_in[0];
    const int* qw = (const int*)d_in[1];
    const unsigned* qz = (const unsigned*)d_in[2];
    const float* sc = (const float*)d_in[3];
    float* out = (float*)d_out;

    const size_t a16_bytes = (size_t)M_TOT * K_TOT * 2;  // 67,108,864
    const size_t wt_bytes  = (size_t)N_TOT * K_TOT * 2;  // 90,177,536

    if (ws_size >= a16_bytes + wt_bytes) {
        _Float16* A16 = (_Float16*)d_ws;
        _Float16* Wt  = (_Float16*)((char*)d_ws + a16_bytes);
        cvt_x_fp16<<<dim3((M_TOT * K_TOT) / (256 * 8)), dim3(256), 0, stream>>>(x, A16);
        dequant_w<<<dim3(N_TOT / 32, 512 / 8), dim3(256), 0, stream>>>(qw, qz, sc, Wt);
        gemm_f16_pl<<<dim3(TNWG), dim3(512), 0, stream>>>(A16, Wt, out);
    } else {
        gptq_fused_gemm<<<dim3(N_TOT / BN, M_TOT / BM), dim3(256), 0, stream>>>(x, qw, qz, sc, out);
    }
}